// Round 8
// baseline (306.755 us; speedup 1.0000x reference)
//
#include <hip/hip_runtime.h>
#include <hip/hip_fp16.h>

#define BSZ 256
#define CCH 512
#define HW_ 81
#define DD 9
#define CH 41472   /* CCH*HW_ */

/* ws layout (floats) */
#define WS_W1T   0        /* [162][81] legacy, unused */
#define WS_TSE   13122    /* [81]  folded se_att bias */
#define WS_S2    13203    /* [512] sa_key bn scale */
#define WS_T2    13715    /* [512] sa_key bn bias */
#define WS_W1S   14227    /* [512][16] folded sa_att_w1 */
#define WS_T1    22419    /* [512] folded sa_att bias */
#define WS_A2    22932    /* [256][64][81] SaMCA attention */
#define WS_ATT   1350036  /* [256][9][512] SeMCA attention */
#define WS_W1F   2529684  /* [96][192] fp16 folded se_att_w1 (ushorts) */
#define WS_K16   2538900  /* [256][41472] fp16 k1 plane (ushorts), flat layout */
#define WS_TOTALP 22931   /* params region end */
#define PREP_N   41363    /* 22931 + 96*192/2 */

typedef _Float16 half8 __attribute__((ext_vector_type(8)));
typedef float f32x4 __attribute__((ext_vector_type(4)));

__device__ __forceinline__ float h2f(unsigned short u) {
    return __half2float(__ushort_as_half(u));
}
__device__ __forceinline__ unsigned short f2h(float f) {
    return __half_as_ushort(__float2half(f));
}

__global__ void prep_kernel(const float* __restrict__ se_att_w1,  // 81*162
                            const float* __restrict__ se_att_bn,  // 4*81
                            const float* __restrict__ sa_key_bn,  // 4*512
                            const float* __restrict__ sa_att_w1,  // 512*16
                            const float* __restrict__ sa_att_bn,  // 4*512
                            float* __restrict__ ws) {
    int idx = blockIdx.x * blockDim.x + threadIdx.x;
    if (idx < 13122) {
        int r = idx / 81, o = idx % 81;
        float g = se_att_bn[o], v = se_att_bn[243 + o];
        float s = g * rsqrtf(v + 1e-5f);
        ws[WS_W1T + idx] = se_att_w1[o * 162 + r] * s;
    } else if (idx < 13203) {
        int o = idx - 13122;
        float g = se_att_bn[o], b = se_att_bn[81 + o], m = se_att_bn[162 + o], v = se_att_bn[243 + o];
        float s = g * rsqrtf(v + 1e-5f);
        ws[WS_TSE + o] = b - m * s;
    } else if (idx < 13715) {
        int c = idx - 13203;
        float g = sa_key_bn[c], v = sa_key_bn[1536 + c];
        ws[WS_S2 + c] = g * rsqrtf(v + 1e-5f);
    } else if (idx < 14227) {
        int c = idx - 13715;
        float g = sa_key_bn[c], b = sa_key_bn[512 + c], m = sa_key_bn[1024 + c], v = sa_key_bn[1536 + c];
        float s = g * rsqrtf(v + 1e-5f);
        ws[WS_T2 + c] = b - m * s;
    } else if (idx < 22419) {
        int e = idx - 14227;
        int o = e >> 4;
        float g = sa_att_bn[o], v = sa_att_bn[1536 + o];
        float s = g * rsqrtf(v + 1e-5f);
        ws[WS_W1S + e] = sa_att_w1[e] * s;
    } else if (idx < WS_TOTALP) {
        int o = idx - 22419;
        float g = sa_att_bn[o], b = sa_att_bn[512 + o], m = sa_att_bn[1024 + o], v = sa_att_bn[1536 + o];
        float s = g * rsqrtf(v + 1e-5f);
        ws[WS_T1 + o] = b - m * s;
    } else if (idx < PREP_N) {
        // fp16 folded W1, padded [96][192] (two ushorts per float slot)
        int e2 = (idx - WS_TOTALP) * 2;
        unsigned int packed = 0;
        #pragma unroll
        for (int q = 0; q < 2; ++q) {
            int e = e2 + q;
            int row = e / 192, k = e - row * 192;
            unsigned short val = 0;
            if (row < 81 && k < 162) {
                float g = se_att_bn[row], v = se_att_bn[243 + row];
                float s = g * rsqrtf(v + 1e-5f);
                val = f2h(se_att_w1[row * 162 + k] * s);
            }
            packed |= ((unsigned int)val) << (16 * q);
        }
        ((unsigned int*)(ws + WS_W1F))[idx - WS_TOTALP] = packed;
    }
}

// ======== Kernel K1: spectral depthwise conv, natural layout ===============
// grid = (batch x 4 channel-tiles), 256 thr, ~26 KB LDS -> 6 blocks/CU.
// In (ch, p) coords the 9 taps are DIFFERENT ROWS at the SAME column range,
// so a [136][84]-padded fp16 plane gives 8B-aligned ushort4 tap reads
// (impossible in flat layout: +-81*tau breaks alignment). Writes fp16 k1
// (flat layout) to ws for se_kernel.
__global__ __launch_bounds__(256) void k1_kernel(
    const float* __restrict__ x,
    const float* __restrict__ se_key_w,   // 81*9
    const float* __restrict__ se_key_b,   // 81
    float* __restrict__ ws)
{
    __shared__ __align__(16) unsigned short xpad[136 * 84]; // 22848 B
    __shared__ __align__(16) float wseP[9 * 84];            //  3024 B [tau][p]
    __shared__ __align__(16) float bseP[84];
    /* ~26.2 KB */

    const int bid = blockIdx.x;
    const int b = bid >> 2;
    const int ct = bid & 3;
    const int c0 = ct * 128;
    const int t = threadIdx.x;
    const float* xb = x + (size_t)b * CH;

    // stage x rows c0-4 .. c0+131 (guard = flat-range guard of reference)
    for (int idx = t; idx < 136 * 81; idx += 256) {
        int r = idx / 81, p = idx - 81 * r;
        int cc = c0 - 4 + r;
        float v = (cc >= 0 && cc < 512) ? xb[cc * 81 + p] : 0.f;
        xpad[r * 84 + p] = f2h(v);
    }
    for (int idx = t; idx < 136 * 3; idx += 256) {
        int r = idx / 3, j = idx - 3 * r;
        xpad[r * 84 + 81 + j] = 0;
    }
    for (int idx = t; idx < 9 * 84; idx += 256) {
        int tau = idx / 84, p = idx - 84 * tau;
        wseP[idx] = (p < 81) ? se_key_w[p * 9 + tau] : 0.f;
    }
    if (t < 84) bseP[t] = (t < 81) ? se_key_b[t] : 0.f;
    __syncthreads();

    unsigned short* k16 = (unsigned short*)(ws + WS_K16) + (size_t)b * CH;
    // vector units: 128 ch x 20 groups (p = 0,4,...,76)
    #pragma unroll 1
    for (int u = t; u < 128 * 20; u += 256) {
        int ch = u / 20, g = u - 20 * (u / 20);
        int p = g * 4;
        float4 bb = *(const float4*)&bseP[p];
        float a0 = bb.x, a1 = bb.y, a2 = bb.z, a3 = bb.w;
        #pragma unroll
        for (int tau = 0; tau < 9; ++tau) {
            ushort4 xr = *(const ushort4*)&xpad[(ch + tau) * 84 + p];
            float4 wr = *(const float4*)&wseP[tau * 84 + p];
            a0 = fmaf(h2f(xr.x), wr.x, a0);
            a1 = fmaf(h2f(xr.y), wr.y, a1);
            a2 = fmaf(h2f(xr.z), wr.z, a2);
            a3 = fmaf(h2f(xr.w), wr.w, a3);
        }
        unsigned short* o = &k16[(size_t)(c0 + ch) * 81 + p];
        o[0] = f2h(a0); o[1] = f2h(a1); o[2] = f2h(a2); o[3] = f2h(a3);
    }
    // scalar tail p = 80
    for (int ch = t; ch < 128; ch += 256) {
        float a = bseP[80];
        #pragma unroll
        for (int tau = 0; tau < 9; ++tau)
            a = fmaf(h2f(xpad[(ch + tau) * 84 + 80]), wseP[tau * 84 + 80], a);
        k16[(size_t)(c0 + ch) * 81 + 80] = f2h(a);
    }
}

// ======== Kernel SA: SaMCA attention, grid = (batch x 4 ch-quarters) ========
// 512 threads; 2 blocks/CU -> 4 waves/SIMD. (round-5 form, unchanged)
__global__ __launch_bounds__(512, 4) void sa_kernel(
    const float* __restrict__ x,
    const float* __restrict__ sa_key_w,   // 512*9
    const float* __restrict__ sa_att_w2,  // 64*8
    const float* __restrict__ sa_att_b2,  // 64
    float* __restrict__ ws)
{
    __shared__ __align__(16) unsigned short xbh[128 * HW_]; // 20736 B fp16 x quarter
    __shared__ float kvf[128 * HW_];                        // 41472 B f32 kv plane
    __shared__ unsigned short wkbL[128 * DD];               //  2304 B
    __shared__ float s2L[128];
    __shared__ float t2L[128];
    __shared__ float w1sL[128 * 16];                        //  8192 B
    __shared__ float saw2L[128];
    __shared__ float b2L[16];
    __shared__ float t1L[128];
    /* total ~74.9 KB */

    const int bid = blockIdx.x;
    const int b = bid >> 2;
    const int qr = bid & 3;
    const int c0 = qr * 128;
    const int t = threadIdx.x;

    // ---- stage ----
    {
        const float4* x4 = (const float4*)(x + (size_t)b * CH + (size_t)c0 * 81);
        for (int v = t; v < 128 * 81 / 4; v += 512) {
            float4 q = x4[v];
            ushort4 s4;
            s4.x = f2h(q.x); s4.y = f2h(q.y); s4.z = f2h(q.z); s4.w = f2h(q.w);
            *(ushort4*)(&xbh[4 * v]) = s4;
        }
        for (int v = t; v < 128 * DD; v += 512) wkbL[v] = f2h(sa_key_w[c0 * 9 + v]);
        if (t < 128) {
            s2L[t] = ws[WS_S2 + c0 + t];
            t2L[t] = ws[WS_T2 + c0 + t];
            saw2L[t] = sa_att_w2[c0 + t];
            t1L[t] = ws[WS_T1 + c0 + t];
        }
        for (int v = t; v < 128 * 16; v += 512) w1sL[v] = ws[WS_W1S + c0 * 16 + v];
        if (t < 16) b2L[t] = sa_att_b2[qr * 16 + t];
    }
    __syncthreads();

    // ---- Pass A: kv = relu(bn(dwconv3x3(x))), f32 into LDS ----
    #pragma unroll 2
    for (int idx = t; idx < 128 * 81; idx += 512) {
        int c = idx / 81, p = idx - 81 * c;
        int y = p / 9, xx = p - 9 * y;
        float conv = 0.f;
        #pragma unroll
        for (int ky = 0; ky < 3; ++ky) {
            int yy = y + ky - 1;
            if (yy < 0 || yy > 8) continue;
            #pragma unroll
            for (int kx = 0; kx < 3; ++kx) {
                int xc = xx + kx - 1;
                if (xc < 0 || xc > 8) continue;
                conv = fmaf(h2f(xbh[c * 81 + yy * 9 + xc]),
                            h2f(wkbL[c * 9 + ky * 3 + kx]), conv);
            }
        }
        kvf[idx] = fmaxf(conv * s2L[c] + t2L[c], 0.f);
    }
    __syncthreads();

    // ---- Pass B: attention logits + softmax ----
    // 16 groups x 32 lanes; lane sub handles pixels p = sub + 32k, k<3.
    {
        const int g = t >> 5, sub = t & 31;
        const int cb = g * 8;                    // local channel base
        float z[8][3];
        #pragma unroll
        for (int o = 0; o < 8; ++o)
            #pragma unroll
            for (int k = 0; k < 3; ++k)
                z[o][k] = t1L[cb + o];

        #pragma unroll 1
        for (int j = 0; j < 8; ++j) {
            float wk[8], wx[8];
            #pragma unroll
            for (int o = 0; o < 8; ++o) {
                wk[o] = w1sL[(cb + o) * 16 + 2 * j];
                wx[o] = w1sL[(cb + o) * 16 + 2 * j + 1];
            }
            const int rowb = (cb + j) * 81;
            #pragma unroll
            for (int k = 0; k < 3; ++k) {
                int p = sub + 32 * k;
                if (p > 80) p = 80;              // clamp; masked at softmax
                float kv = kvf[rowb + p];
                float xv = h2f(xbh[rowb + p]);
                #pragma unroll
                for (int o = 0; o < 8; ++o) {
                    z[o][k] = fmaf(wk[o], kv, z[o][k]);
                    z[o][k] = fmaf(wx[o], xv, z[o][k]);
                }
            }
        }

        float a2v[3];
        const float b2g = b2L[g];
        #pragma unroll
        for (int k = 0; k < 3; ++k) {
            float s = b2g;
            #pragma unroll
            for (int o = 0; o < 8; ++o)
                s = fmaf(saw2L[cb + o], fmaxf(z[o][k], 0.f), s);
            int p = sub + 32 * k;
            a2v[k] = (p < 81) ? s : -1e30f;
        }

        float m = a2v[0];
        #pragma unroll
        for (int k = 1; k < 3; ++k) m = fmaxf(m, a2v[k]);
        #pragma unroll
        for (int off = 1; off < 32; off <<= 1) m = fmaxf(m, __shfl_xor(m, off, 64));
        float ls = 0.f;
        float ev[3];
        #pragma unroll
        for (int k = 0; k < 3; ++k) { ev[k] = __expf(a2v[k] - m); ls += ev[k]; }
        #pragma unroll
        for (int off = 1; off < 32; off <<= 1) ls += __shfl_xor(ls, off, 64);
        float inv = 1.f / ls;

        float* a2out = ws + WS_A2 + (size_t)b * 5184 + (size_t)(qr * 16 + g) * 81;
        #pragma unroll
        for (int k = 0; k < 3; ++k) {
            int p = sub + 32 * k;
            if (p < 81) a2out[p] = ev[k] * inv;
        }
    }
}

// ======== Kernel SE: SeMCA attention via MFMA, grid = (batch x 4 quarters) ==
// Round-8: conv hoisted to k1_kernel -> se is copy + MFMA only. LDS 55 KB
// -> 2 blocks/CU, 512 thr -> 16 waves/CU = 4 waves/SIMD (was 1 block,
// 2 waves/SIMD). Build = two independent coalesced global-read loops.
__global__ __launch_bounds__(512) void se_kernel(
    const float* __restrict__ x,
    const float* __restrict__ se_att_w2,  // 9*81
    const float* __restrict__ se_att_b2,  // 9
    float* __restrict__ ws)
{
    __shared__ __align__(16) unsigned short kqs[128 * 200];  // 51200 B [col][k]
    __shared__ float w2L[DD * 96];                           //  3456 B
    __shared__ float tseL[96];
    /* ~55.1 KB */

    const int pb = blockIdx.x;
    const int b = pb >> 2;
    const int q = pb & 3;
    const int c0 = q * 128;
    const int t = threadIdx.x;

    for (int v = t; v < DD * 96; v += 512) {
        int d = v / 96, row = v - 96 * d;
        w2L[v] = (row < 81) ? se_att_w2[d * 81 + row] : 0.f;
    }
    if (t < 96) tseL[t] = (t < 81) ? ws[WS_TSE + t] : 0.f;
    // zero-pad kqs rows 162..199 (fp16 garbage could be Inf/NaN in MFMA)
    for (int v = t; v < 128 * 38; v += 512) {
        int k = v >> 7, jl = v & 127;
        kqs[jl * 200 + 162 + k] = 0;
    }
    // q-rows (k < 81): KQ[k][j] = x.flat[k*512 + c0 + j], coalesced fp32
    {
        const float* xb = x + (size_t)b * CH + c0;
        const int jl = t & 127;
        int k = t >> 7;
        #pragma unroll 3
        for (; k < 81; k += 4)
            kqs[jl * 200 + k] = f2h(xb[k * 512 + jl]);
    }
    // k-rows (81 <= k < 162): precomputed fp16 k1, coalesced
    {
        const unsigned short* k16 =
            (const unsigned short*)(ws + WS_K16) + (size_t)b * CH + c0;
        const int jl = t & 127;
        int kk = t >> 7;
        #pragma unroll 3
        for (; kk < 81; kk += 4)
            kqs[jl * 200 + 81 + kk] = k16[kk * 512 + jl];
    }
    __syncthreads();

    // MFMA: C[96 x 128] = W1f[96 x 192] * KQ[192 x 128]
    const int wv = t >> 6;          // wave 0..7, owns 16 cols
    const int lane = t & 63;
    const int quad = lane >> 4;
    const int l15 = lane & 15;
    const unsigned short* w1f = (const unsigned short*)(ws + WS_W1F);
    float* attout = ws + WS_ATT + (size_t)b * 4608;

    f32x4 acc[6];
    #pragma unroll
    for (int m = 0; m < 6; ++m) acc[m] = (f32x4){0.f, 0.f, 0.f, 0.f};

    #pragma unroll 1
    for (int pass = 0; pass < 6; ++pass) {
        half8 bfr = *(const half8*)&kqs[(wv * 16 + l15) * 200 + pass * 32 + quad * 8];
        #pragma unroll
        for (int m = 0; m < 6; ++m) {
            half8 afr = *(const half8*)&w1f[(m * 16 + l15) * 192 + pass * 32 + quad * 8];
            acc[m] = __builtin_amdgcn_mfma_f32_16x16x32_f16(afr, bfr, acc[m], 0, 0, 0);
        }
    }

    // epilogue: relu(C + tse) -> fold 9x81 -> softmax -> ws ATT
    float pd[9];
    #pragma unroll
    for (int d = 0; d < 9; ++d) pd[d] = 0.f;
    #pragma unroll
    for (int m = 0; m < 6; ++m) {
        #pragma unroll
        for (int reg = 0; reg < 4; ++reg) {
            int row = m * 16 + quad * 4 + reg;
            float z = fmaxf(acc[m][reg] + tseL[row], 0.f);
            #pragma unroll
            for (int d = 0; d < 9; ++d)
                pd[d] = fmaf(w2L[d * 96 + row], z, pd[d]);
        }
    }
    #pragma unroll
    for (int d = 0; d < 9; ++d) {
        pd[d] += __shfl_xor(pd[d], 16, 64);
        pd[d] += __shfl_xor(pd[d], 32, 64);
    }
    if (quad == 0) {
        int j = c0 + wv * 16 + l15;
        float ad[9];
        #pragma unroll
        for (int d = 0; d < 9; ++d) ad[d] = pd[d] + se_att_b2[d];
        float mm = ad[0];
        #pragma unroll
        for (int d = 1; d < 9; ++d) mm = fmaxf(mm, ad[d]);
        float ls = 0.f;
        #pragma unroll
        for (int d = 0; d < 9; ++d) { ad[d] = __expf(ad[d] - mm); ls += ad[d]; }
        float inv = 1.f / ls;
        #pragma unroll
        for (int d = 0; d < 9; ++d) attout[d * 512 + j] = ad[d] * inv;
    }
}

// ============== Kernel B: combine, block = (batch, 64-channel tile) =========
// Row-vectorized (round-7 form, unchanged).
#define CS 108   /* channel stride in padded plane (9 rows * 12) */
#define RS 12    /* row stride */

__device__ __forceinline__ void ldrow_h(const unsigned short* base, float* r) {
    ushort4 a = *(const ushort4*)(base);
    ushort4 bq = *(const ushort4*)(base + 4);
    unsigned short c = base[8];
    r[0] = h2f(a.x); r[1] = h2f(a.y); r[2] = h2f(a.z); r[3] = h2f(a.w);
    r[4] = h2f(bq.x); r[5] = h2f(bq.y); r[6] = h2f(bq.z); r[7] = h2f(bq.w);
    r[8] = h2f(c);
}
__device__ __forceinline__ void ldrow_f(const float* base, float* r) {
    float4 a = *(const float4*)(base);
    float4 bq = *(const float4*)(base + 4);
    r[0] = a.x; r[1] = a.y; r[2] = a.z; r[3] = a.w;
    r[4] = bq.x; r[5] = bq.y; r[6] = bq.z; r[7] = bq.w;
    r[8] = base[8];
}
__device__ __forceinline__ void zrow(float* r) {
    #pragma unroll
    for (int xx = 0; xx < 9; ++xx) r[xx] = 0.f;
}

__global__ __launch_bounds__(256) void combine_kernel(
    const float* __restrict__ x,
    const float* __restrict__ alpha,
    const float* __restrict__ sa_key_w,   // 512*9
    const float* __restrict__ se_key_w,   // 81*9
    const float* __restrict__ se_key_b,   // 81
    const float* __restrict__ se_val_w,   // 512*9
    const float* __restrict__ se_val_b,   // 512
    const float* __restrict__ ws,
    float* __restrict__ out)
{
    __shared__ __align__(16) unsigned short xsh[72 * CS];  // 15552 B fp16 padded
    __shared__ __align__(16) unsigned short vsh[72 * CS];  // 15552 B fp16 padded
    __shared__ __align__(16) float wsePad[9 * CS];         //  3888 B [tau][y][12]
    __shared__ __align__(16) float bsePad[CS];             //   432 B [y][12]
    __shared__ __align__(16) float a2Pad[8 * CS];          //  3456 B [g][y][12]
    __shared__ float wvL[72 * 9];                          //  2592 B
    __shared__ float bvL[72];
    __shared__ float wkL[64 * 9];                          //  2304 B
    __shared__ float s2L[64];
    __shared__ float t2L[64];
    __shared__ float attL[9 * 64];                         //  2304 B
    /* ~45.9 KB -> 3 blocks/CU */

    const int bid = blockIdx.x;
    const int b = bid >> 3;
    const int tile = bid & 7;
    const int c0 = tile * 64;
    const int t = threadIdx.x;
    const int f0 = (c0 - 4) * 81;          // divisible by 4

    // ---- stage x into padded fp16 plane (guarded float4 reads) ----
    {
        const float* xg = x + (size_t)b * CH;
        for (int v4 = t; v4 < 1458; v4 += 256) {
            int lf = v4 * 4;
            int gf = f0 + lf;
            float4 q = (gf >= 0 && gf < CH) ? *(const float4*)(xg + gf)
                                            : (float4){0.f, 0.f, 0.f, 0.f};
            #pragma unroll
            for (int j = 0; j < 4; ++j) {
                int lfj = lf + j;
                int i = lfj / 81, p = lfj - 81 * i;
                int yy = p / 9, xx = p - 9 * yy;
                xsh[i * CS + yy * RS + xx] = f2h(((const float*)&q)[j]);
            }
        }
    }
    // ---- stage weights ----
    for (int idx = t; idx < 648; idx += 256) {
        int cc = c0 - 4 + idx / 9;
        wvL[idx] = (cc >= 0 && cc < 512) ? se_val_w[cc * 9 + idx % 9] : 0.f;
    }
    if (t < 72) {
        int cc = c0 - 4 + t;
        bvL[t] = (cc >= 0 && cc < 512) ? se_val_b[cc] : 0.f;
    }
    for (int idx = t; idx < 576; idx += 256) wkL[idx] = sa_key_w[c0 * 9 + idx];
    if (t < 64) { s2L[t] = ws[WS_S2 + c0 + t]; t2L[t] = ws[WS_T2 + c0 + t]; }
    for (int idx = t; idx < 972; idx += 256) {
        int tau = idx / CS, r = idx - CS * tau;
        int yy = r / RS, xx = r - RS * yy;
        if (xx < 9) wsePad[idx] = se_key_w[(yy * 9 + xx) * 9 + tau];
    }
    if (t < CS) {
        int yy = t / RS, xx = t - RS * yy;
        if (xx < 9) bsePad[t] = se_key_b[yy * 9 + xx];
    }
    for (int idx = t; idx < 864; idx += 256) {
        int g = idx / CS, r = idx - CS * g;
        int yy = r / RS, xx = r - RS * yy;
        if (xx < 9)
            a2Pad[idx] = ws[WS_A2 + (size_t)b * 5184 + (size_t)(tile * 8 + g) * 81 + yy * 9 + xx];
    }
    for (int idx = t; idx < 576; idx += 256)
        attL[idx] = ws[WS_ATT + (size_t)b * 4608 + (idx >> 6) * 512 + c0 + (idx & 63)];
    __syncthreads();

    // ---- v-plane: dwconv3x3 + bias, row-vectorized -> padded fp16 plane ----
    #pragma unroll 1
    for (int u = t; u < 648; u += 256) {
        int i = u / 9, yy = u - 9 * i;
        const int cb = i * CS;
        float q0[9], q1[9], q2[9];
        if (yy > 0) ldrow_h(&xsh[cb + (yy - 1) * RS], q0);
        else zrow(q0);
        ldrow_h(&xsh[cb + yy * RS], q1);
        if (yy < 8) ldrow_h(&xsh[cb + (yy + 1) * RS], q2);
        else zrow(q2);
        float wv[9];
        #pragma unroll
        for (int j = 0; j < 9; ++j) wv[j] = wvL[i * 9 + j];
        const float bv = bvL[i];
        float o[9];
        #pragma unroll
        for (int xx = 0; xx < 9; ++xx) {
            float s = bv;
            #pragma unroll
            for (int kx = 0; kx < 3; ++kx) {
                int xc = xx + kx - 1;
                if (xc >= 0 && xc <= 8) {
                    s = fmaf(q0[xc], wv[kx], s);
                    s = fmaf(q1[xc], wv[3 + kx], s);
                    s = fmaf(q2[xc], wv[6 + kx], s);
                }
            }
            o[xx] = s;     // OOB channels: wv=bv=0 and xsh=0 -> 0 (= pad_v)
        }
        const int vb = cb + yy * RS;
        ushort4 wA, wB;
        wA.x = f2h(o[0]); wA.y = f2h(o[1]); wA.z = f2h(o[2]); wA.w = f2h(o[3]);
        wB.x = f2h(o[4]); wB.y = f2h(o[5]); wB.z = f2h(o[6]); wB.w = f2h(o[7]);
        *(ushort4*)(&vsh[vb]) = wA;
        *(ushort4*)(&vsh[vb + 4]) = wB;
        vsh[vb + 8] = f2h(o[8]);
    }
    __syncthreads();

    // ---- main: unit = (cl, y) -> 9 outputs via row loads ----
    const float av = alpha[0];
    #pragma unroll 1
    for (int u = t; u < 576; u += 256) {
        int cl = u / 9, yy = u - 9 * cl;
        const int rb = yy * RS;
        float acc[9];
        ldrow_f(&bsePad[rb], acc);                 // k1se bias
        float r1[9];
        #pragma unroll
        for (int tau = 0; tau < 9; ++tau) {
            float xr[9], wr[9];
            ldrow_h(&xsh[(cl + tau) * CS + rb], xr);
            ldrow_f(&wsePad[tau * CS + rb], wr);
            #pragma unroll
            for (int xx = 0; xx < 9; ++xx) acc[xx] = fmaf(xr[xx], wr[xx], acc[xx]);
            if (tau == 4) {
                #pragma unroll
                for (int xx = 0; xx < 9; ++xx) r1[xx] = xr[xx];  // center row
            }
        }
        #pragma unroll
        for (int d = 0; d < 9; ++d) {
            float vr[9];
            ldrow_h(&vsh[(cl + d) * CS + rb], vr);
            const float ad = attL[d * 64 + cl];
            #pragma unroll
            for (int xx = 0; xx < 9; ++xx) acc[xx] = fmaf(vr[xx], ad, acc[xx]);
        }
        float r0[9], r2[9];
        if (yy > 0) ldrow_h(&xsh[(cl + 4) * CS + rb - RS], r0);
        else zrow(r0);
        if (yy < 8) ldrow_h(&xsh[(cl + 4) * CS + rb + RS], r2);
        else zrow(r2);
        float wkr[9];
        #pragma unroll
        for (int j = 0; j < 9; ++j) wkr[j] = wkL[cl * 9 + j];
        const float s2 = s2L[cl], t2v = t2L[cl];
        float a2r[9];
        ldrow_f(&a2Pad[(cl >> 3) * CS + rb], a2r);
        float* orow = out + (size_t)b * CH + (size_t)(c0 + cl) * 81 + yy * 9;
        #pragma unroll
        for (int xx = 0; xx < 9; ++xx) {
            float sk = 0.f;
            #pragma unroll
            for (int kx = 0; kx < 3; ++kx) {
                int xc = xx + kx - 1;
                if (xc >= 0 && xc <= 8) {
                    sk = fmaf(r0[xc], wkr[kx], sk);
                    sk = fmaf(r1[xc], wkr[3 + kx], sk);
                    sk = fmaf(r2[xc], wkr[6 + kx], sk);
                }
            }
            float k1s = fmaxf(sk * s2 + t2v, 0.f);
            float out2 = k1s + a2r[xx] * r1[xx];
            orow[xx] = av * acc[xx] + (1.f - av) * out2;
        }
    }
}

extern "C" void kernel_launch(void* const* d_in, const int* in_sizes, int n_in,
                              void* d_out, int out_size, void* d_ws, size_t ws_size,
                              hipStream_t stream) {
    const float* x          = (const float*)d_in[0];
    const float* alpha      = (const float*)d_in[1];
    const float* sa_key_w   = (const float*)d_in[2];
    const float* sa_key_bn  = (const float*)d_in[3];
    const float* sa_att_w1  = (const float*)d_in[4];
    const float* sa_att_bn  = (const float*)d_in[5];
    const float* sa_att_w2  = (const float*)d_in[6];
    const float* sa_att_b2  = (const float*)d_in[7];
    const float* se_key_w   = (const float*)d_in[8];
    const float* se_key_b   = (const float*)d_in[9];
    const float* se_att_w1  = (const float*)d_in[10];
    const float* se_att_bn  = (const float*)d_in[11];
    const float* se_att_w2  = (const float*)d_in[12];
    const float* se_att_b2  = (const float*)d_in[13];
    const float* se_val_w   = (const float*)d_in[14];
    const float* se_val_b   = (const float*)d_in[15];
    float* ws = (float*)d_ws;
    float* outp = (float*)d_out;

    prep_kernel<<<(PREP_N + 255) / 256, 256, 0, stream>>>(
        se_att_w1, se_att_bn, sa_key_bn, sa_att_w1, sa_att_bn, ws);
    k1_kernel<<<BSZ * 4, 256, 0, stream>>>(
        x, se_key_w, se_key_b, ws);
    sa_kernel<<<BSZ * 4, 512, 0, stream>>>(
        x, sa_key_w, sa_att_w2, sa_att_b2, ws);
    se_kernel<<<BSZ * 4, 512, 0, stream>>>(
        x, se_att_w2, se_att_b2, ws);
    combine_kernel<<<BSZ * 8, 256, 0, stream>>>(
        x, alpha, sa_key_w, se_key_w, se_key_b, se_val_w, se_val_b, ws, outp);
}